// Round 5
// baseline (10338.094 us; speedup 1.0000x reference)
//
#include <hip/hip_runtime.h>
#include <hip/hip_bf16.h>

typedef __hip_bfloat16 bf16;
typedef __attribute__((ext_vector_type(8))) __bf16 bf16x8;
typedef __attribute__((ext_vector_type(4))) float f32x4;

#define N_NODES 32768
#define N_EDGES 262144
#define DIM 768
#define NGR 64
#define KIN 800     // 784 padded to 32
#define KSTACK 6912 // self(768) + 8*768
#define NKEY (N_NODES * 8)

#define GLOBAL_AS __attribute__((address_space(1)))
#define LDS_AS __attribute__((address_space(3)))

__device__ __forceinline__ float gelu_f(float x) {
    return 0.5f * x * (1.0f + erff(x * 0.70710678118654752f));
}
__device__ __forceinline__ float bfu(unsigned short v) {
    union { unsigned u; float f; } x; x.u = (unsigned)v << 16; return x.f;
}
__device__ __forceinline__ unsigned short fbf(float f) {
    bf16 t = __float2bfloat16(f); return *(unsigned short*)&t;
}

// ---------------------------------------------------------------------------
// Transpose + cast fp32 [I][O] -> bf16 [O][ostride], zero-pad i in [I,Ipad)
__global__ __launch_bounds__(256)
void tcast_k(const float* __restrict__ in, bf16* __restrict__ out, int I, int O,
             int Ipad, int ostride) {
    __shared__ float t[32][33];
    const int i0 = blockIdx.x * 32, o0 = blockIdx.y * 32;
    const int tx = threadIdx.x & 31, ty = threadIdx.x >> 5;
#pragma unroll
    for (int q = 0; q < 4; ++q) {
        int i = i0 + ty + q * 8, o = o0 + tx;
        t[ty + q * 8][tx] = (i < I) ? in[(size_t)i * O + o] : 0.0f;
    }
    __syncthreads();
#pragma unroll
    for (int q = 0; q < 4; ++q) {
        int o = o0 + ty + q * 8, i = i0 + tx;
        if (i < Ipad) out[(size_t)o * ostride + i] = __float2bfloat16(t[tx][ty + q * 8]);
    }
}

// ---------------------------------------------------------------------------
// RGCN weights -> Wst[l][768 out][6912 K], K order: [self | r0..r7]. grid(24,24,27)
__global__ __launch_bounds__(256)
void wprep_k(const float* __restrict__ W_rel, const float* __restrict__ W_loop,
             bf16* __restrict__ Wst) {
    __shared__ float t[32][33];
    const int z = blockIdx.z, l = z / 9, q = z % 9;
    const float* in = (q < 8) ? W_rel + ((size_t)(l * 8 + q)) * DIM * DIM
                              : W_loop + (size_t)l * DIM * DIM;
    bf16* out = Wst + (size_t)l * DIM * KSTACK + (q < 8 ? (q + 1) * DIM : 0);
    const int i0 = blockIdx.x * 32, o0 = blockIdx.y * 32;
    const int tx = threadIdx.x & 31, ty = threadIdx.x >> 5;
#pragma unroll
    for (int qq = 0; qq < 4; ++qq)
        t[ty + qq * 8][tx] = in[(size_t)(i0 + ty + qq * 8) * DIM + o0 + tx];
    __syncthreads();
#pragma unroll
    for (int qq = 0; qq < 4; ++qq)
        out[(size_t)(o0 + ty + qq * 8) * KSTACK + i0 + tx] =
            __float2bfloat16(t[tx][ty + qq * 8]);
}

// ---------------------------------------------------------------------------
__global__ __launch_bounds__(256)
void concat_k(const float* __restrict__ tv, const float* __restrict__ cv, bf16* __restrict__ X) {
    const int n = blockIdx.x;
    for (int c = threadIdx.x; c < KIN; c += 256) {
        float v = 0.0f;
        if (c < 16) v = tv[(size_t)n * 16 + c];
        else if (c < 784) v = cv[(size_t)n * DIM + (c - 16)];
        X[(size_t)n * KIN + c] = __float2bfloat16(v);
    }
}

// ---------------------------------------------------------------------------
// CSR build over key = dst*8 + type
__global__ __launch_bounds__(256)
void hist2_k(const int* __restrict__ dst, const int* __restrict__ et, int* __restrict__ deg) {
    int e = blockIdx.x * 256 + threadIdx.x;
    if (e < N_EDGES) atomicAdd(&deg[dst[e] * 8 + et[e]], 1);
}

__global__ __launch_bounds__(1024)
void scan2_k(const int* __restrict__ deg, int* __restrict__ rp, int* __restrict__ cur) {
    __shared__ int part[1024];
    const int t = threadIdx.x;
    const int base_i = t * 256;
    int s = 0;
    for (int i = 0; i < 256; ++i) s += deg[base_i + i];
    part[t] = s; __syncthreads();
    for (int st = 1; st < 1024; st <<= 1) {
        int v = (t >= st) ? part[t - st] : 0;
        __syncthreads();
        part[t] += v;
        __syncthreads();
    }
    int run = part[t] - s;
    for (int i = 0; i < 256; ++i) {
        int d = deg[base_i + i];
        rp[base_i + i] = run; cur[base_i + i] = run;
        run += d;
    }
    if (t == 1023) rp[NKEY] = run;
}

__global__ __launch_bounds__(256)
void place2_k(const int* __restrict__ src, const int* __restrict__ dst,
              const int* __restrict__ et, int* __restrict__ cur, int* __restrict__ eidx) {
    int e = blockIdx.x * 256 + threadIdx.x;
    if (e >= N_EDGES) return;
    int pos = atomicAdd(&cur[dst[e] * 8 + et[e]], 1);
    eidx[pos] = src[e];
}

// ---------------------------------------------------------------------------
// Gather-aggregate for NC relations [rbase, rbase+NC), exact CSR ranges.
template <int NC>
__global__ __launch_bounds__(256)
void gather2_k(const bf16* __restrict__ h, const int* __restrict__ rp2,
               const int* __restrict__ eidx, bf16* __restrict__ AGG, int rbase) {
    const int wave = threadIdx.x >> 6, lane = threadIdx.x & 63;
    const int n = blockIdx.x * 4 + wave;
    const int c0 = 2 * lane;
    unsigned short* outrow = (unsigned short*)&AGG[(size_t)n * (NC * DIM)];
    const int* bp = &rp2[n * 8 + rbase];
#pragma unroll 1
    for (int sel = 0; sel < NC; ++sel) {
        const int s = bp[sel], e = bp[sel + 1];
        float2 f[6] = {};
        for (int t = s; t < e; ++t) {
            const unsigned short* hs = (const unsigned short*)&h[(size_t)eidx[t] * DIM];
#pragma unroll
            for (int j = 0; j < 6; ++j) {
                ushort2 u = *(const ushort2*)&hs[c0 + j * 128];
                f[j].x += bfu(u.x); f[j].y += bfu(u.y);
            }
        }
#pragma unroll
        for (int j = 0; j < 6; ++j) {
            ushort2 o; o.x = fbf(f[j].x); o.y = fbf(f[j].y);
            *(ushort2*)&outrow[sel * DIM + c0 + j * 128] = o;
        }
    }
}

// ---------------------------------------------------------------------------
// gemm256: C[M,Nn](f32) (+)= A[M,Ktot] @ BT[Nn,Ktot]^T. BM=128, BN=256, BK=32.
// 512 thr = 8 waves (2 row x 4 col). Double-buffered LDS + counted vmcnt
// pipeline (T3/T4): issue next-tile global_load_lds FIRST, s_waitcnt vmcnt(3)
// (never 0 mid-loop), raw s_barrier; chunk-XOR LDS swizzle (source-side
// pre-swizzle + matching ds_read swizzle). XCD-chunked block swizzle.
template <int ACCUM>
__global__ __launch_bounds__(512, 6)
void gemm256(const bf16* __restrict__ A1, int S1, int K1,
             const bf16* __restrict__ A2, int S2,
             const bf16* __restrict__ BT, int ldb,
             float* __restrict__ OUT, int Nn, int Ktot, int nbx) {
    __shared__ __align__(16) unsigned short lA[2][128 * 32];
    __shared__ __align__(16) unsigned short lB[2][256 * 32];
    const int nblk = gridDim.x;
    const int qx = nblk >> 3;
    const int bid = blockIdx.x;
    const int wgid = (bid & 7) * qx + (bid >> 3);
    const int bx = wgid % nbx, by = wgid / nbx;
    const int bn = bx * 256, bm = by * 128;
    const int tid = threadIdx.x;
    const int wave = tid >> 6, lane = tid & 63;
    const int wr = wave >> 2, wc = wave & 3;
    const int l15 = lane & 15, lg = lane >> 4;
    // swizzled chunk offset for ds_read (involution of the source swizzle)
    const int swz = (lg ^ (l15 & 3)) * 8;

    f32x4 acc[4][4] = {};

    const int nt = Ktot >> 5;

    // stage K-tile t into LDS buffer buf (3 global_load_lds per thread)
    auto stage = [&](int t, int buf) {
        const int k0 = t * 32;
        const bf16* Ab; int koff, stA;
        if (k0 < K1) { Ab = A1; koff = k0; stA = S1; }
        else         { Ab = A2; koff = k0 - K1; stA = S2; }
        {
            const int row = tid >> 2, k8 = tid & 3;
            const int ks = k8 ^ (row & 3);  // pre-swizzled source chunk
            const bf16* ga = Ab + (size_t)(bm + row) * stA + koff + ks * 8;
            __builtin_amdgcn_global_load_lds((const GLOBAL_AS void*)ga,
                (LDS_AS void*)&lA[buf][(wave * 64) * 8], 16, 0, 0);
        }
#pragma unroll
        for (int qq = 0; qq < 2; ++qq) {
            const int c = qq * 512 + tid;
            const int row = c >> 2, k8 = c & 3;
            const int ks = k8 ^ (row & 3);
            const bf16* gb = BT + (size_t)(bn + row) * ldb + k0 + ks * 8;
            __builtin_amdgcn_global_load_lds((const GLOBAL_AS void*)gb,
                (LDS_AS void*)&lB[buf][((qq * 8 + wave) * 64) * 8], 16, 0, 0);
        }
    };

    stage(0, 0);

    for (int t = 0; t < nt; ++t) {
        const int cur = t & 1;
        if (t + 1 < nt) {
            stage(t + 1, cur ^ 1);
            asm volatile("s_waitcnt vmcnt(3)" ::: "memory");
        } else {
            asm volatile("s_waitcnt vmcnt(0)" ::: "memory");
        }
        __builtin_amdgcn_s_barrier();
        __builtin_amdgcn_sched_barrier(0);

        bf16x8 af[4], bfr[4];
#pragma unroll
        for (int mi = 0; mi < 4; ++mi) {
            const int r = wr * 64 + mi * 16 + l15;
            af[mi] = *reinterpret_cast<const bf16x8*>(&lA[cur][r * 32 + swz]);
        }
#pragma unroll
        for (int ni = 0; ni < 4; ++ni) {
            const int r = wc * 64 + ni * 16 + l15;
            bfr[ni] = *reinterpret_cast<const bf16x8*>(&lB[cur][r * 32 + swz]);
        }
        __builtin_amdgcn_s_setprio(1);
#pragma unroll
        for (int mi = 0; mi < 4; ++mi)
#pragma unroll
            for (int ni = 0; ni < 4; ++ni)
                acc[mi][ni] = __builtin_amdgcn_mfma_f32_16x16x32_bf16(af[mi], bfr[ni], acc[mi][ni], 0, 0, 0);
        __builtin_amdgcn_s_setprio(0);
        __builtin_amdgcn_sched_barrier(0);
        __builtin_amdgcn_s_barrier();
    }

#pragma unroll
    for (int mi = 0; mi < 4; ++mi)
#pragma unroll
        for (int ni = 0; ni < 4; ++ni) {
            const int r0 = bm + wr * 64 + mi * 16 + lg * 4;
            const int c0 = bn + wc * 64 + ni * 16 + l15;
#pragma unroll
            for (int i = 0; i < 4; ++i) {
                size_t idx = (size_t)(r0 + i) * Nn + c0;
                float v = acc[mi][ni][i];
                if (ACCUM) v += OUT[idx];
                OUT[idx] = v;
            }
        }
}

// ---------------------------------------------------------------------------
// Legacy 128x128 GEMM (gate GEMM only, Nn=384)
template <int ACCUM>
__global__ __launch_bounds__(256, 2)
void gemm_bt(const bf16* __restrict__ A1, int S1, int K1,
             const bf16* __restrict__ A2, int S2,
             const bf16* __restrict__ BT, int ldb,
             float* __restrict__ OUT, int Nn, int Ktot) {
    __shared__ __align__(16) unsigned short lA[128 * 32];
    __shared__ __align__(16) unsigned short lB[128 * 32];
    const int bn = blockIdx.x * 128;
    const int bm = blockIdx.y * 128;
    const int tid = threadIdx.x;
    const int wave = tid >> 6, lane = tid & 63;
    const int wr = wave >> 1, wc = wave & 1;
    const int l15 = lane & 15, lg = lane >> 4;

    f32x4 acc[4][4] = {};

    for (int k0 = 0; k0 < Ktot; k0 += 32) {
        const bf16* Ab; int koff, stA;
        if (k0 < K1) { Ab = A1; koff = k0; stA = S1; }
        else         { Ab = A2; koff = k0 - K1; stA = S2; }
#pragma unroll
        for (int q = 0; q < 2; ++q) {
            int c = wave * 128 + q * 64 + lane;
            int row = c >> 2, k8 = c & 3;
            const bf16* ga = Ab + (size_t)(bm + row) * stA + koff + k8 * 8;
            const bf16* gb = BT + (size_t)(bn + row) * ldb + k0 + k8 * 8;
            __builtin_amdgcn_global_load_lds((const GLOBAL_AS void*)ga,
                (LDS_AS void*)&lA[(wave * 128 + q * 64) * 8], 16, 0, 0);
            __builtin_amdgcn_global_load_lds((const GLOBAL_AS void*)gb,
                (LDS_AS void*)&lB[(wave * 128 + q * 64) * 8], 16, 0, 0);
        }
        __syncthreads();
        bf16x8 af[4], bfr[4];
#pragma unroll
        for (int mi = 0; mi < 4; ++mi)
            af[mi] = *reinterpret_cast<const bf16x8*>(&lA[(wr * 64 + mi * 16 + l15) * 32 + lg * 8]);
#pragma unroll
        for (int ni = 0; ni < 4; ++ni)
            bfr[ni] = *reinterpret_cast<const bf16x8*>(&lB[(wc * 64 + ni * 16 + l15) * 32 + lg * 8]);
#pragma unroll
        for (int mi = 0; mi < 4; ++mi)
#pragma unroll
            for (int ni = 0; ni < 4; ++ni)
                acc[mi][ni] = __builtin_amdgcn_mfma_f32_16x16x32_bf16(af[mi], bfr[ni], acc[mi][ni], 0, 0, 0);
        __syncthreads();
    }

#pragma unroll
    for (int mi = 0; mi < 4; ++mi)
#pragma unroll
        for (int ni = 0; ni < 4; ++ni) {
            const int r0 = bm + wr * 64 + mi * 16 + lg * 4;
            const int c0 = bn + wc * 64 + ni * 16 + l15;
#pragma unroll
            for (int i = 0; i < 4; ++i) {
                size_t idx = (size_t)(r0 + i) * Nn + c0;
                float v = acc[mi][ni][i];
                if (ACCUM) v += OUT[idx];
                OUT[idx] = v;
            }
        }
}

// ---------------------------------------------------------------------------
// Fused bias + LayerNorm + GELU; wave per row. grid N/4, block 256.
__global__ __launch_bounds__(256)
void ln_gelu_k(const float* __restrict__ ACC, const float* __restrict__ bias,
               const float* __restrict__ g, const float* __restrict__ b,
               bf16* __restrict__ hout) {
    const int wave = threadIdx.x >> 6, lane = threadIdx.x & 63;
    const int n = blockIdx.x * 4 + wave;
    float x[12];
    float s = 0.f, ss = 0.f;
#pragma unroll
    for (int j = 0; j < 12; ++j) {
        int c = lane + j * 64;
        x[j] = ACC[(size_t)n * DIM + c] + bias[c];
        s += x[j]; ss += x[j] * x[j];
    }
#pragma unroll
    for (int m = 1; m < 64; m <<= 1) { s += __shfl_xor(s, m, 64); ss += __shfl_xor(ss, m, 64); }
    const float mean = s * (1.f / DIM);
    const float var = ss * (1.f / DIM) - mean * mean;
    const float rstd = rsqrtf(var + 1e-5f);
#pragma unroll
    for (int j = 0; j < 12; ++j) {
        int c = lane + j * 64;
        float y = (x[j] - mean) * rstd * g[c] + b[c];
        hout[(size_t)n * DIM + c] = __float2bfloat16(gelu_f(y));
    }
}

// ---------------------------------------------------------------------------
__global__ __launch_bounds__(256)
void gate_k(const float* __restrict__ G1, const float* __restrict__ bg1,
            const float* __restrict__ Wg2, const float* __restrict__ bg2,
            float* __restrict__ gate) {
    const int wave = threadIdx.x >> 6, lane = threadIdx.x & 63;
    const int n = blockIdx.x * 4 + wave;
    float acc = 0.f;
#pragma unroll
    for (int j = 0; j < 6; ++j) {
        int c = lane + j * 64;
        float xv = G1[(size_t)n * 384 + c] + bg1[c];
        acc += gelu_f(xv) * Wg2[c];
    }
#pragma unroll
    for (int m = 1; m < 64; m <<= 1) acc += __shfl_xor(acc, m, 64);
    if (lane == 0) gate[n] = acc + bg2[0];
}

// ---------------------------------------------------------------------------
__device__ __forceinline__ int lower_bound_ng(const int* ng, int key) {
    int lo = 0, hi = N_NODES;
    while (lo < hi) { int mid = (lo + hi) >> 1; if (ng[mid] < key) lo = mid + 1; else hi = mid; }
    return lo;
}

__global__ __launch_bounds__(256)
void seg_stats_k(const float* __restrict__ gate, const int* __restrict__ ng,
                 float* __restrict__ gmax, float* __restrict__ gden) {
    __shared__ float red[256];
    const int b = blockIdx.x, t = threadIdx.x;
    const int start = lower_bound_ng(ng, b), end = lower_bound_ng(ng, b + 1);
    float m = -1e30f;
    for (int n = start + t; n < end; n += 256) m = fmaxf(m, gate[n]);
    red[t] = m; __syncthreads();
    for (int s = 128; s > 0; s >>= 1) { if (t < s) red[t] = fmaxf(red[t], red[t + s]); __syncthreads(); }
    const float gm = red[0]; __syncthreads();
    float ssum = 0.f;
    for (int n = start + t; n < end; n += 256) ssum += expf(gate[n] - gm);
    red[t] = ssum; __syncthreads();
    for (int s = 128; s > 0; s >>= 1) { if (t < s) red[t] += red[t + s]; __syncthreads(); }
    if (t == 0) { gmax[b] = gm; gden[b] = fmaxf(red[0], 1e-30f); }
}

__global__ __launch_bounds__(768)
void pool_k(const bf16* __restrict__ h, const float* __restrict__ gate,
            const int* __restrict__ ng, const float* __restrict__ gmax,
            const float* __restrict__ gden, float* __restrict__ grep) {
    const int b = blockIdx.x, c = threadIdx.x;
    const int start = lower_bound_ng(ng, b), end = lower_bound_ng(ng, b + 1);
    const float gm = gmax[b], inv = 1.0f / gden[b];
    const unsigned short* hv = (const unsigned short*)h;
    float a0 = 0.f, a1 = 0.f;
    int n = start;
    for (; n + 1 < end; n += 2) {
        float w0 = expf(gate[n] - gm) * inv;
        float w1 = expf(gate[n + 1] - gm) * inv;
        a0 += w0 * bfu(hv[(size_t)n * DIM + c]);
        a1 += w1 * bfu(hv[(size_t)(n + 1) * DIM + c]);
    }
    if (n < end) a0 += expf(gate[n] - gm) * inv * bfu(hv[(size_t)n * DIM + c]);
    grep[(size_t)b * DIM + c] = a0 + a1;
}

// ---------------------------------------------------------------------------
__global__ __launch_bounds__(512)
void cls_k(const float* __restrict__ grep, const float* __restrict__ Wc1,
           const float* __restrict__ bc1, const float* __restrict__ lng,
           const float* __restrict__ lnb, const float* __restrict__ Wc2,
           const float* __restrict__ bc2, float* __restrict__ out) {
    __shared__ float gr[DIM];
    __shared__ float red[512];
    const int b = blockIdx.x, j = threadIdx.x;
    for (int c = j; c < DIM; c += 512) gr[c] = grep[(size_t)b * DIM + c];
    __syncthreads();
    float a = bc1[j];
#pragma unroll 4
    for (int k = 0; k < DIM; ++k) a = fmaf(gr[k], Wc1[(size_t)k * 512 + j], a);
    red[j] = a; __syncthreads();
    for (int s = 256; s > 0; s >>= 1) { if (j < s) red[j] += red[j + s]; __syncthreads(); }
    const float mean = red[0] * (1.f / 512.f);
    __syncthreads();
    red[j] = (a - mean) * (a - mean); __syncthreads();
    for (int s = 256; s > 0; s >>= 1) { if (j < s) red[j] += red[j + s]; __syncthreads(); }
    const float rstd = rsqrtf(red[0] * (1.f / 512.f) + 1e-5f);
    __syncthreads();
    const float z = gelu_f((a - mean) * rstd * lng[j] + lnb[j]);
    red[j] = z * Wc2[2 * j + 0]; __syncthreads();
    for (int s = 256; s > 0; s >>= 1) { if (j < s) red[j] += red[j + s]; __syncthreads(); }
    const float l0 = red[0] + bc2[0];
    __syncthreads();
    red[j] = z * Wc2[2 * j + 1]; __syncthreads();
    for (int s = 256; s > 0; s >>= 1) { if (j < s) red[j] += red[j + s]; __syncthreads(); }
    if (j == 0) {
        const float l1 = red[0] + bc2[1];
        const float mx = fmaxf(l0, l1);
        const float lse = mx + logf(expf(l0 - mx) + expf(l1 - mx));
        out[2 * b + 0] = l0 - lse;
        out[2 * b + 1] = l1 - lse;
    }
}

// ---------------------------------------------------------------------------
extern "C" void kernel_launch(void* const* d_in, const int* in_sizes, int n_in,
                              void* d_out, int out_size, void* d_ws, size_t ws_size,
                              hipStream_t stream) {
    const float* type_vec = (const float*)d_in[0];
    const float* code_vec = (const float*)d_in[1];
    const float* W_in     = (const float*)d_in[2];
    const float* b_in     = (const float*)d_in[3];
    const float* ln_in_g  = (const float*)d_in[4];
    const float* ln_in_b  = (const float*)d_in[5];
    const float* W_rel    = (const float*)d_in[6];
    const float* W_loop   = (const float*)d_in[7];
    const float* rgcn_bias= (const float*)d_in[8];
    const float* ln_g     = (const float*)d_in[9];
    const float* ln_b     = (const float*)d_in[10];
    const float* Wg1      = (const float*)d_in[11];
    const float* bg1      = (const float*)d_in[12];
    const float* Wg2      = (const float*)d_in[13];
    const float* bg2      = (const float*)d_in[14];
    const float* Wc1      = (const float*)d_in[15];
    const float* bc1      = (const float*)d_in[16];
    const float* ln_c_g   = (const float*)d_in[17];
    const float* ln_c_b   = (const float*)d_in[18];
    const float* Wc2      = (const float*)d_in[19];
    const float* bc2      = (const float*)d_in[20];
    const int* src        = (const int*)d_in[21];
    const int* dst        = (const int*)d_in[22];
    const int* etype      = (const int*)d_in[23];
    const int* node_graph = (const int*)d_in[24];

    char* ws = (char*)d_ws;

    // pick relation-chunk width nc by workspace size
    auto need = [](int nc) -> size_t {
        size_t base = 0;
        auto al = [&](size_t sz) { base = (base + sz + 255) & ~(size_t)255; };
        al((size_t)N_NODES * DIM * 2);        // H
        al((size_t)N_NODES * DIM * 4);        // ACC
        al((size_t)DIM * KIN * 2);            // WIN
        al((size_t)3 * DIM * KSTACK * 2);     // WST
        al((size_t)384 * DIM * 2);            // WG1
        size_t open = base;
        al((size_t)N_NODES * nc * DIM * 2);   // AGG
        al((size_t)(NKEY + 1) * 4);           // RP2
        al((size_t)NKEY * 4);                 // CUR2
        al((size_t)NKEY * 4);                 // DEG2
        al((size_t)N_EDGES * 4);              // EIX
        al((size_t)N_NODES * 4);              // GATE
        al(256); al(256);                     // GMAX, GDEN
        al((size_t)NGR * DIM * 4);            // GREP
        size_t xend = open + (size_t)N_NODES * KIN * 2;
        return base > xend ? base : xend;
    };
    int nc = 1;
    if (ws_size >= need(4)) nc = 4;
    else if (ws_size >= need(2)) nc = 2;

    // layout
    size_t off = 0;
    auto alloc = [&](size_t sz) { size_t r = off; off = (off + sz + 255) & ~(size_t)255; return r; };
    bf16*  h_bf  = (bf16*)(ws + alloc((size_t)N_NODES * DIM * 2));
    float* ACC   = (float*)(ws + alloc((size_t)N_NODES * DIM * 4));
    bf16*  WinT  = (bf16*)(ws + alloc((size_t)DIM * KIN * 2));
    bf16*  Wst   = (bf16*)(ws + alloc((size_t)3 * DIM * KSTACK * 2));
    bf16*  Wg1T  = (bf16*)(ws + alloc((size_t)384 * DIM * 2));
    size_t open  = off;
    bf16*  AGG   = (bf16*)(ws + alloc((size_t)N_NODES * nc * DIM * 2));
    int*   rp2   = (int*)(ws + alloc((size_t)(NKEY + 1) * 4));
    int*   cur2  = (int*)(ws + alloc((size_t)NKEY * 4));
    int*   deg2  = (int*)(ws + alloc((size_t)NKEY * 4));
    int*   eidx  = (int*)(ws + alloc((size_t)N_EDGES * 4));
    float* gate  = (float*)(ws + alloc((size_t)N_NODES * 4));
    float* gmax  = (float*)(ws + alloc(256));
    float* gden  = (float*)(ws + alloc(256));
    float* grep  = (float*)(ws + alloc((size_t)NGR * DIM * 4));
    bf16*  Xbf   = (bf16*)(ws + open);      // [N][800]; dead after input GEMM
    float* G1    = ACC;                     // reuse after layers

    // --- weight prep
    tcast_k<<<dim3(25, 24), 256, 0, stream>>>(W_in, WinT, 784, DIM, KIN, KIN);
    wprep_k<<<dim3(24, 24, 27), 256, 0, stream>>>(W_rel, W_loop, Wst);
    tcast_k<<<dim3(24, 12), 256, 0, stream>>>(Wg1, Wg1T, DIM, 384, DIM, DIM);

    // --- input projection (X overlaps AGG/CSR region; consumed before they're written)
    concat_k<<<N_NODES, 256, 0, stream>>>(type_vec, code_vec, Xbf);
    gemm256<0><<<768, 512, 0, stream>>>(Xbf, KIN, KIN, Xbf, KIN, WinT, KIN, ACC, DIM, KIN, 3);
    ln_gelu_k<<<N_NODES / 4, 256, 0, stream>>>(ACC, b_in, ln_in_g, ln_in_b, h_bf);

    // --- (dst,type) CSR build (after X is dead)
    hipMemsetAsync(deg2, 0, (size_t)NKEY * 4, stream);
    hist2_k<<<N_EDGES / 256, 256, 0, stream>>>(dst, etype, deg2);
    scan2_k<<<1, 1024, 0, stream>>>(deg2, rp2, cur2);
    place2_k<<<N_EDGES / 256, 256, 0, stream>>>(src, dst, etype, cur2, eidx);

    // --- RGCN layers: per chunk of nc relations, gather then accumulate-GEMM
    const int nchunks = 8 / nc;
    for (int l = 0; l < 3; ++l) {
        bf16* Wl = Wst + (size_t)l * DIM * KSTACK;
        for (int c = 0; c < nchunks; ++c) {
            const int rbase = c * nc;
            if (nc == 1)      gather2_k<1><<<N_NODES / 4, 256, 0, stream>>>(h_bf, rp2, eidx, AGG, rbase);
            else if (nc == 2) gather2_k<2><<<N_NODES / 4, 256, 0, stream>>>(h_bf, rp2, eidx, AGG, rbase);
            else              gather2_k<4><<<N_NODES / 4, 256, 0, stream>>>(h_bf, rp2, eidx, AGG, rbase);
            if (c == 0) {
                gemm256<0><<<768, 512, 0, stream>>>(
                    h_bf, DIM, DIM, AGG, nc * DIM, Wl, KSTACK, ACC, DIM, DIM + nc * DIM, 3);
            } else {
                gemm256<1><<<768, 512, 0, stream>>>(
                    AGG, nc * DIM, nc * DIM, AGG, nc * DIM,
                    Wl + (size_t)DIM * (1 + rbase), KSTACK, ACC, DIM, nc * DIM, 3);
            }
        }
        ln_gelu_k<<<N_NODES / 4, 256, 0, stream>>>(ACC, rgcn_bias + l * DIM, ln_g + l * DIM,
                                                   ln_b + l * DIM, h_bf);
    }

    // --- global attention pooling
    gemm_bt<0><<<dim3(3, 256), 256, 0, stream>>>(
        h_bf, DIM, DIM, h_bf, DIM, Wg1T, DIM, G1, 384, DIM);
    gate_k<<<N_NODES / 4, 256, 0, stream>>>(G1, bg1, Wg2, bg2, gate);
    seg_stats_k<<<NGR, 256, 0, stream>>>(gate, node_graph, gmax, gden);
    pool_k<<<NGR, 768, 0, stream>>>(h_bf, gate, node_graph, gmax, gden, grep);

    // --- classifier head
    cls_k<<<NGR, 512, 0, stream>>>(grep, Wc1, bc1, ln_c_g, ln_c_b, Wc2, bc2, (float*)d_out);
}

// Round 6
// 2718.325 us; speedup vs baseline: 3.8031x; 3.8031x over previous
//
#include <hip/hip_runtime.h>
#include <hip/hip_bf16.h>

typedef __hip_bfloat16 bf16;
typedef __attribute__((ext_vector_type(8))) __bf16 bf16x8;
typedef __attribute__((ext_vector_type(4))) float f32x4;

#define N_NODES 32768
#define N_EDGES 262144
#define DIM 768
#define NGR 64
#define KIN 800     // 784 padded to 32
#define KSTACK 6912 // self(768) + 8*768
#define NKEY (N_NODES * 8)

#define GLOBAL_AS __attribute__((address_space(1)))
#define LDS_AS __attribute__((address_space(3)))

__device__ __forceinline__ float gelu_f(float x) {
    return 0.5f * x * (1.0f + erff(x * 0.70710678118654752f));
}
__device__ __forceinline__ float bfu(unsigned short v) {
    union { unsigned u; float f; } x; x.u = (unsigned)v << 16; return x.f;
}
__device__ __forceinline__ unsigned short fbf(float f) {
    bf16 t = __float2bfloat16(f); return *(unsigned short*)&t;
}

// ---------------------------------------------------------------------------
// Transpose + cast fp32 [I][O] -> bf16 [O][ostride], zero-pad i in [I,Ipad)
__global__ __launch_bounds__(256)
void tcast_k(const float* __restrict__ in, bf16* __restrict__ out, int I, int O,
             int Ipad, int ostride) {
    __shared__ float t[32][33];
    const int i0 = blockIdx.x * 32, o0 = blockIdx.y * 32;
    const int tx = threadIdx.x & 31, ty = threadIdx.x >> 5;
#pragma unroll
    for (int q = 0; q < 4; ++q) {
        int i = i0 + ty + q * 8, o = o0 + tx;
        t[ty + q * 8][tx] = (i < I) ? in[(size_t)i * O + o] : 0.0f;
    }
    __syncthreads();
#pragma unroll
    for (int q = 0; q < 4; ++q) {
        int o = o0 + ty + q * 8, i = i0 + tx;
        if (i < Ipad) out[(size_t)o * ostride + i] = __float2bfloat16(t[tx][ty + q * 8]);
    }
}

// ---------------------------------------------------------------------------
// RGCN weights -> Wst[l][768 out][6912 K], K order: [self | r0..r7]. grid(24,24,27)
__global__ __launch_bounds__(256)
void wprep_k(const float* __restrict__ W_rel, const float* __restrict__ W_loop,
             bf16* __restrict__ Wst) {
    __shared__ float t[32][33];
    const int z = blockIdx.z, l = z / 9, q = z % 9;
    const float* in = (q < 8) ? W_rel + ((size_t)(l * 8 + q)) * DIM * DIM
                              : W_loop + (size_t)l * DIM * DIM;
    bf16* out = Wst + (size_t)l * DIM * KSTACK + (q < 8 ? (q + 1) * DIM : 0);
    const int i0 = blockIdx.x * 32, o0 = blockIdx.y * 32;
    const int tx = threadIdx.x & 31, ty = threadIdx.x >> 5;
#pragma unroll
    for (int qq = 0; qq < 4; ++qq)
        t[ty + qq * 8][tx] = in[(size_t)(i0 + ty + qq * 8) * DIM + o0 + tx];
    __syncthreads();
#pragma unroll
    for (int qq = 0; qq < 4; ++qq)
        out[(size_t)(o0 + ty + qq * 8) * KSTACK + i0 + tx] =
            __float2bfloat16(t[tx][ty + qq * 8]);
}

// ---------------------------------------------------------------------------
__global__ __launch_bounds__(256)
void concat_k(const float* __restrict__ tv, const float* __restrict__ cv, bf16* __restrict__ X) {
    const int n = blockIdx.x;
    for (int c = threadIdx.x; c < KIN; c += 256) {
        float v = 0.0f;
        if (c < 16) v = tv[(size_t)n * 16 + c];
        else if (c < 784) v = cv[(size_t)n * DIM + (c - 16)];
        X[(size_t)n * KIN + c] = __float2bfloat16(v);
    }
}

// ---------------------------------------------------------------------------
// CSR build over key = dst*8 + type
__global__ __launch_bounds__(256)
void hist2_k(const int* __restrict__ dst, const int* __restrict__ et, int* __restrict__ deg) {
    int e = blockIdx.x * 256 + threadIdx.x;
    if (e < N_EDGES) atomicAdd(&deg[dst[e] * 8 + et[e]], 1);
}

__global__ __launch_bounds__(1024)
void scan2_k(const int* __restrict__ deg, int* __restrict__ rp, int* __restrict__ cur) {
    __shared__ int part[1024];
    const int t = threadIdx.x;
    const int base_i = t * 256;
    int s = 0;
    for (int i = 0; i < 256; ++i) s += deg[base_i + i];
    part[t] = s; __syncthreads();
    for (int st = 1; st < 1024; st <<= 1) {
        int v = (t >= st) ? part[t - st] : 0;
        __syncthreads();
        part[t] += v;
        __syncthreads();
    }
    int run = part[t] - s;
    for (int i = 0; i < 256; ++i) {
        int d = deg[base_i + i];
        rp[base_i + i] = run; cur[base_i + i] = run;
        run += d;
    }
    if (t == 1023) rp[NKEY] = run;
}

__global__ __launch_bounds__(256)
void place2_k(const int* __restrict__ src, const int* __restrict__ dst,
              const int* __restrict__ et, int* __restrict__ cur, int* __restrict__ eidx) {
    int e = blockIdx.x * 256 + threadIdx.x;
    if (e >= N_EDGES) return;
    int pos = atomicAdd(&cur[dst[e] * 8 + et[e]], 1);
    eidx[pos] = src[e];
}

// ---------------------------------------------------------------------------
// Gather-aggregate for NC relations [rbase, rbase+NC), exact CSR ranges.
template <int NC>
__global__ __launch_bounds__(256)
void gather2_k(const bf16* __restrict__ h, const int* __restrict__ rp2,
               const int* __restrict__ eidx, bf16* __restrict__ AGG, int rbase) {
    const int wave = threadIdx.x >> 6, lane = threadIdx.x & 63;
    const int n = blockIdx.x * 4 + wave;
    const int c0 = 2 * lane;
    unsigned short* outrow = (unsigned short*)&AGG[(size_t)n * (NC * DIM)];
    const int* bp = &rp2[n * 8 + rbase];
#pragma unroll 1
    for (int sel = 0; sel < NC; ++sel) {
        const int s = bp[sel], e = bp[sel + 1];
        float2 f[6] = {};
        for (int t = s; t < e; ++t) {
            const unsigned short* hs = (const unsigned short*)&h[(size_t)eidx[t] * DIM];
#pragma unroll
            for (int j = 0; j < 6; ++j) {
                ushort2 u = *(const ushort2*)&hs[c0 + j * 128];
                f[j].x += bfu(u.x); f[j].y += bfu(u.y);
            }
        }
#pragma unroll
        for (int j = 0; j < 6; ++j) {
            ushort2 o; o.x = fbf(f[j].x); o.y = fbf(f[j].y);
            *(ushort2*)&outrow[sel * DIM + c0 + j * 128] = o;
        }
    }
}

// ---------------------------------------------------------------------------
// gemm256: C[M,Nn](f32) (+)= A[M,Ktot] @ BT[Nn,Ktot]^T. BM=128, BN=256, BK=32.
// 512 thr = 8 waves (2 row x 4 col). Double-buffered LDS + counted vmcnt
// pipeline: issue next-tile global_load_lds FIRST, s_waitcnt vmcnt(3)
// (never 0 mid-loop), raw s_barrier; chunk-XOR LDS swizzle (source-side
// pre-swizzle + matching ds_read swizzle). XCD-chunked block swizzle.
// launch_bounds(512,4): 128-VGPR cap -- fits the ~116-reg working set
// (acc in AGPRs); (512,6) spilled acc to scratch (round-5 disaster).
template <int ACCUM>
__global__ __launch_bounds__(512, 4)
void gemm256(const bf16* __restrict__ A1, int S1, int K1,
             const bf16* __restrict__ A2, int S2,
             const bf16* __restrict__ BT, int ldb,
             float* __restrict__ OUT, int Nn, int Ktot, int nbx) {
    __shared__ __align__(16) unsigned short lA[2][128 * 32];
    __shared__ __align__(16) unsigned short lB[2][256 * 32];
    const int nblk = gridDim.x;
    const int qx = nblk >> 3;
    const int bid = blockIdx.x;
    const int wgid = (bid & 7) * qx + (bid >> 3);
    const int bx = wgid % nbx, by = wgid / nbx;
    const int bn = bx * 256, bm = by * 128;
    const int tid = threadIdx.x;
    const int wave = tid >> 6, lane = tid & 63;
    const int wr = wave >> 2, wc = wave & 3;
    const int l15 = lane & 15, lg = lane >> 4;
    // swizzled chunk offset for ds_read (involution of the source swizzle)
    const int swz = (lg ^ (l15 & 3)) * 8;

    f32x4 acc[4][4] = {};

    const int nt = Ktot >> 5;

    // stage K-tile t into LDS buffer buf (3 global_load_lds per thread)
    auto stage = [&](int t, int buf) {
        const int k0 = t * 32;
        const bf16* Ab; int koff, stA;
        if (k0 < K1) { Ab = A1; koff = k0; stA = S1; }
        else         { Ab = A2; koff = k0 - K1; stA = S2; }
        {
            const int row = tid >> 2, k8 = tid & 3;
            const int ks = k8 ^ (row & 3);  // pre-swizzled source chunk
            const bf16* ga = Ab + (size_t)(bm + row) * stA + koff + ks * 8;
            __builtin_amdgcn_global_load_lds((const GLOBAL_AS void*)ga,
                (LDS_AS void*)&lA[buf][(wave * 64) * 8], 16, 0, 0);
        }
#pragma unroll
        for (int qq = 0; qq < 2; ++qq) {
            const int c = qq * 512 + tid;
            const int row = c >> 2, k8 = c & 3;
            const int ks = k8 ^ (row & 3);
            const bf16* gb = BT + (size_t)(bn + row) * ldb + k0 + ks * 8;
            __builtin_amdgcn_global_load_lds((const GLOBAL_AS void*)gb,
                (LDS_AS void*)&lB[buf][((qq * 8 + wave) * 64) * 8], 16, 0, 0);
        }
    };

    stage(0, 0);

    for (int t = 0; t < nt; ++t) {
        const int cur = t & 1;
        if (t + 1 < nt) {
            stage(t + 1, cur ^ 1);
            asm volatile("s_waitcnt vmcnt(3)" ::: "memory");
        } else {
            asm volatile("s_waitcnt vmcnt(0)" ::: "memory");
        }
        __builtin_amdgcn_s_barrier();
        __builtin_amdgcn_sched_barrier(0);

        bf16x8 af[4], bfr[4];
#pragma unroll
        for (int mi = 0; mi < 4; ++mi) {
            const int r = wr * 64 + mi * 16 + l15;
            af[mi] = *reinterpret_cast<const bf16x8*>(&lA[cur][r * 32 + swz]);
        }
#pragma unroll
        for (int ni = 0; ni < 4; ++ni) {
            const int r = wc * 64 + ni * 16 + l15;
            bfr[ni] = *reinterpret_cast<const bf16x8*>(&lB[cur][r * 32 + swz]);
        }
        __builtin_amdgcn_s_setprio(1);
#pragma unroll
        for (int mi = 0; mi < 4; ++mi)
#pragma unroll
            for (int ni = 0; ni < 4; ++ni)
                acc[mi][ni] = __builtin_amdgcn_mfma_f32_16x16x32_bf16(af[mi], bfr[ni], acc[mi][ni], 0, 0, 0);
        __builtin_amdgcn_s_setprio(0);
        __builtin_amdgcn_sched_barrier(0);
        __builtin_amdgcn_s_barrier();
    }

#pragma unroll
    for (int mi = 0; mi < 4; ++mi)
#pragma unroll
        for (int ni = 0; ni < 4; ++ni) {
            const int r0 = bm + wr * 64 + mi * 16 + lg * 4;
            const int c0 = bn + wc * 64 + ni * 16 + l15;
#pragma unroll
            for (int i = 0; i < 4; ++i) {
                size_t idx = (size_t)(r0 + i) * Nn + c0;
                float v = acc[mi][ni][i];
                if (ACCUM) v += OUT[idx];
                OUT[idx] = v;
            }
        }
}

// ---------------------------------------------------------------------------
// Legacy 128x128 GEMM (gate GEMM only, Nn=384)
template <int ACCUM>
__global__ __launch_bounds__(256, 2)
void gemm_bt(const bf16* __restrict__ A1, int S1, int K1,
             const bf16* __restrict__ A2, int S2,
             const bf16* __restrict__ BT, int ldb,
             float* __restrict__ OUT, int Nn, int Ktot) {
    __shared__ __align__(16) unsigned short lA[128 * 32];
    __shared__ __align__(16) unsigned short lB[128 * 32];
    const int bn = blockIdx.x * 128;
    const int bm = blockIdx.y * 128;
    const int tid = threadIdx.x;
    const int wave = tid >> 6, lane = tid & 63;
    const int wr = wave >> 1, wc = wave & 1;
    const int l15 = lane & 15, lg = lane >> 4;

    f32x4 acc[4][4] = {};

    for (int k0 = 0; k0 < Ktot; k0 += 32) {
        const bf16* Ab; int koff, stA;
        if (k0 < K1) { Ab = A1; koff = k0; stA = S1; }
        else         { Ab = A2; koff = k0 - K1; stA = S2; }
#pragma unroll
        for (int q = 0; q < 2; ++q) {
            int c = wave * 128 + q * 64 + lane;
            int row = c >> 2, k8 = c & 3;
            const bf16* ga = Ab + (size_t)(bm + row) * stA + koff + k8 * 8;
            const bf16* gb = BT + (size_t)(bn + row) * ldb + k0 + k8 * 8;
            __builtin_amdgcn_global_load_lds((const GLOBAL_AS void*)ga,
                (LDS_AS void*)&lA[(wave * 128 + q * 64) * 8], 16, 0, 0);
            __builtin_amdgcn_global_load_lds((const GLOBAL_AS void*)gb,
                (LDS_AS void*)&lB[(wave * 128 + q * 64) * 8], 16, 0, 0);
        }
        __syncthreads();
        bf16x8 af[4], bfr[4];
#pragma unroll
        for (int mi = 0; mi < 4; ++mi)
            af[mi] = *reinterpret_cast<const bf16x8*>(&lA[(wr * 64 + mi * 16 + l15) * 32 + lg * 8]);
#pragma unroll
        for (int ni = 0; ni < 4; ++ni)
            bfr[ni] = *reinterpret_cast<const bf16x8*>(&lB[(wc * 64 + ni * 16 + l15) * 32 + lg * 8]);
#pragma unroll
        for (int mi = 0; mi < 4; ++mi)
#pragma unroll
            for (int ni = 0; ni < 4; ++ni)
                acc[mi][ni] = __builtin_amdgcn_mfma_f32_16x16x32_bf16(af[mi], bfr[ni], acc[mi][ni], 0, 0, 0);
        __syncthreads();
    }

#pragma unroll
    for (int mi = 0; mi < 4; ++mi)
#pragma unroll
        for (int ni = 0; ni < 4; ++ni) {
            const int r0 = bm + wr * 64 + mi * 16 + lg * 4;
            const int c0 = bn + wc * 64 + ni * 16 + l15;
#pragma unroll
            for (int i = 0; i < 4; ++i) {
                size_t idx = (size_t)(r0 + i) * Nn + c0;
                float v = acc[mi][ni][i];
                if (ACCUM) v += OUT[idx];
                OUT[idx] = v;
            }
        }
}

// ---------------------------------------------------------------------------
// Fused bias + LayerNorm + GELU; wave per row. grid N/4, block 256.
__global__ __launch_bounds__(256)
void ln_gelu_k(const float* __restrict__ ACC, const float* __restrict__ bias,
               const float* __restrict__ g, const float* __restrict__ b,
               bf16* __restrict__ hout) {
    const int wave = threadIdx.x >> 6, lane = threadIdx.x & 63;
    const int n = blockIdx.x * 4 + wave;
    float x[12];
    float s = 0.f, ss = 0.f;
#pragma unroll
    for (int j = 0; j < 12; ++j) {
        int c = lane + j * 64;
        x[j] = ACC[(size_t)n * DIM + c] + bias[c];
        s += x[j]; ss += x[j] * x[j];
    }
#pragma unroll
    for (int m = 1; m < 64; m <<= 1) { s += __shfl_xor(s, m, 64); ss += __shfl_xor(ss, m, 64); }
    const float mean = s * (1.f / DIM);
    const float var = ss * (1.f / DIM) - mean * mean;
    const float rstd = rsqrtf(var + 1e-5f);
#pragma unroll
    for (int j = 0; j < 12; ++j) {
        int c = lane + j * 64;
        float y = (x[j] - mean) * rstd * g[c] + b[c];
        hout[(size_t)n * DIM + c] = __float2bfloat16(gelu_f(y));
    }
}

// ---------------------------------------------------------------------------
__global__ __launch_bounds__(256)
void gate_k(const float* __restrict__ G1, const float* __restrict__ bg1,
            const float* __restrict__ Wg2, const float* __restrict__ bg2,
            float* __restrict__ gate) {
    const int wave = threadIdx.x >> 6, lane = threadIdx.x & 63;
    const int n = blockIdx.x * 4 + wave;
    float acc = 0.f;
#pragma unroll
    for (int j = 0; j < 6; ++j) {
        int c = lane + j * 64;
        float xv = G1[(size_t)n * 384 + c] + bg1[c];
        acc += gelu_f(xv) * Wg2[c];
    }
#pragma unroll
    for (int m = 1; m < 64; m <<= 1) acc += __shfl_xor(acc, m, 64);
    if (lane == 0) gate[n] = acc + bg2[0];
}

// ---------------------------------------------------------------------------
__device__ __forceinline__ int lower_bound_ng(const int* ng, int key) {
    int lo = 0, hi = N_NODES;
    while (lo < hi) { int mid = (lo + hi) >> 1; if (ng[mid] < key) lo = mid + 1; else hi = mid; }
    return lo;
}

__global__ __launch_bounds__(256)
void seg_stats_k(const float* __restrict__ gate, const int* __restrict__ ng,
                 float* __restrict__ gmax, float* __restrict__ gden) {
    __shared__ float red[256];
    const int b = blockIdx.x, t = threadIdx.x;
    const int start = lower_bound_ng(ng, b), end = lower_bound_ng(ng, b + 1);
    float m = -1e30f;
    for (int n = start + t; n < end; n += 256) m = fmaxf(m, gate[n]);
    red[t] = m; __syncthreads();
    for (int s = 128; s > 0; s >>= 1) { if (t < s) red[t] = fmaxf(red[t], red[t + s]); __syncthreads(); }
    const float gm = red[0]; __syncthreads();
    float ssum = 0.f;
    for (int n = start + t; n < end; n += 256) ssum += expf(gate[n] - gm);
    red[t] = ssum; __syncthreads();
    for (int s = 128; s > 0; s >>= 1) { if (t < s) red[t] += red[t + s]; __syncthreads(); }
    if (t == 0) { gmax[b] = gm; gden[b] = fmaxf(red[0], 1e-30f); }
}

__global__ __launch_bounds__(768)
void pool_k(const bf16* __restrict__ h, const float* __restrict__ gate,
            const int* __restrict__ ng, const float* __restrict__ gmax,
            const float* __restrict__ gden, float* __restrict__ grep) {
    const int b = blockIdx.x, c = threadIdx.x;
    const int start = lower_bound_ng(ng, b), end = lower_bound_ng(ng, b + 1);
    const float gm = gmax[b], inv = 1.0f / gden[b];
    const unsigned short* hv = (const unsigned short*)h;
    float a0 = 0.f, a1 = 0.f;
    int n = start;
    for (; n + 1 < end; n += 2) {
        float w0 = expf(gate[n] - gm) * inv;
        float w1 = expf(gate[n + 1] - gm) * inv;
        a0 += w0 * bfu(hv[(size_t)n * DIM + c]);
        a1 += w1 * bfu(hv[(size_t)(n + 1) * DIM + c]);
    }
    if (n < end) a0 += expf(gate[n] - gm) * inv * bfu(hv[(size_t)n * DIM + c]);
    grep[(size_t)b * DIM + c] = a0 + a1;
}

// ---------------------------------------------------------------------------
__global__ __launch_bounds__(512)
void cls_k(const float* __restrict__ grep, const float* __restrict__ Wc1,
           const float* __restrict__ bc1, const float* __restrict__ lng,
           const float* __restrict__ lnb, const float* __restrict__ Wc2,
           const float* __restrict__ bc2, float* __restrict__ out) {
    __shared__ float gr[DIM];
    __shared__ float red[512];
    const int b = blockIdx.x, j = threadIdx.x;
    for (int c = j; c < DIM; c += 512) gr[c] = grep[(size_t)b * DIM + c];
    __syncthreads();
    float a = bc1[j];
#pragma unroll 4
    for (int k = 0; k < DIM; ++k) a = fmaf(gr[k], Wc1[(size_t)k * 512 + j], a);
    red[j] = a; __syncthreads();
    for (int s = 256; s > 0; s >>= 1) { if (j < s) red[j] += red[j + s]; __syncthreads(); }
    const float mean = red[0] * (1.f / 512.f);
    __syncthreads();
    red[j] = (a - mean) * (a - mean); __syncthreads();
    for (int s = 256; s > 0; s >>= 1) { if (j < s) red[j] += red[j + s]; __syncthreads(); }
    const float rstd = rsqrtf(red[0] * (1.f / 512.f) + 1e-5f);
    __syncthreads();
    const float z = gelu_f((a - mean) * rstd * lng[j] + lnb[j]);
    red[j] = z * Wc2[2 * j + 0]; __syncthreads();
    for (int s = 256; s > 0; s >>= 1) { if (j < s) red[j] += red[j + s]; __syncthreads(); }
    const float l0 = red[0] + bc2[0];
    __syncthreads();
    red[j] = z * Wc2[2 * j + 1]; __syncthreads();
    for (int s = 256; s > 0; s >>= 1) { if (j < s) red[j] += red[j + s]; __syncthreads(); }
    if (j == 0) {
        const float l1 = red[0] + bc2[1];
        const float mx = fmaxf(l0, l1);
        const float lse = mx + logf(expf(l0 - mx) + expf(l1 - mx));
        out[2 * b + 0] = l0 - lse;
        out[2 * b + 1] = l1 - lse;
    }
}

// ---------------------------------------------------------------------------
extern "C" void kernel_launch(void* const* d_in, const int* in_sizes, int n_in,
                              void* d_out, int out_size, void* d_ws, size_t ws_size,
                              hipStream_t stream) {
    const float* type_vec = (const float*)d_in[0];
    const float* code_vec = (const float*)d_in[1];
    const float* W_in     = (const float*)d_in[2];
    const float* b_in     = (const float*)d_in[3];
    const float* ln_in_g  = (const float*)d_in[4];
    const float* ln_in_b  = (const float*)d_in[5];
    const float* W_rel    = (const float*)d_in[6];
    const float* W_loop   = (const float*)d_in[7];
    const float* rgcn_bias= (const float*)d_in[8];
    const float* ln_g     = (const float*)d_in[9];
    const float* ln_b     = (const float*)d_in[10];
    const float* Wg1      = (const float*)d_in[11];
    const float* bg1      = (const float*)d_in[12];
    const float* Wg2      = (const float*)d_in[13];
    const float* bg2      = (const float*)d_in[14];
    const float* Wc1      = (const float*)d_in[15];
    const float* bc1      = (const float*)d_in[16];
    const float* ln_c_g   = (const float*)d_in[17];
    const float* ln_c_b   = (const float*)d_in[18];
    const float* Wc2      = (const float*)d_in[19];
    const float* bc2      = (const float*)d_in[20];
    const int* src        = (const int*)d_in[21];
    const int* dst        = (const int*)d_in[22];
    const int* etype      = (const int*)d_in[23];
    const int* node_graph = (const int*)d_in[24];

    char* ws = (char*)d_ws;

    // pick relation-chunk width nc by workspace size
    auto need = [](int nc) -> size_t {
        size_t base = 0;
        auto al = [&](size_t sz) { base = (base + sz + 255) & ~(size_t)255; };
        al((size_t)N_NODES * DIM * 2);        // H
        al((size_t)N_NODES * DIM * 4);        // ACC
        al((size_t)DIM * KIN * 2);            // WIN
        al((size_t)3 * DIM * KSTACK * 2);     // WST
        al((size_t)384 * DIM * 2);            // WG1
        size_t open = base;
        al((size_t)N_NODES * nc * DIM * 2);   // AGG
        al((size_t)(NKEY + 1) * 4);           // RP2
        al((size_t)NKEY * 4);                 // CUR2
        al((size_t)NKEY * 4);                 // DEG2
        al((size_t)N_EDGES * 4);              // EIX
        al((size_t)N_NODES * 4);              // GATE
        al(256); al(256);                     // GMAX, GDEN
        al((size_t)NGR * DIM * 4);            // GREP
        size_t xend = open + (size_t)N_NODES * KIN * 2;
        return base > xend ? base : xend;
    };
    int nc = 1;
    if (ws_size >= need(4)) nc = 4;
    else if (ws_size >= need(2)) nc = 2;

    // layout
    size_t off = 0;
    auto alloc = [&](size_t sz) { size_t r = off; off = (off + sz + 255) & ~(size_t)255; return r; };
    bf16*  h_bf  = (bf16*)(ws + alloc((size_t)N_NODES * DIM * 2));
    float* ACC   = (float*)(ws + alloc((size_t)N_NODES * DIM * 4));
    bf16*  WinT  = (bf16*)(ws + alloc((size_t)DIM * KIN * 2));
    bf16*  Wst   = (bf16*)(ws + alloc((size_t)3 * DIM * KSTACK * 2));
    bf16*  Wg1T  = (bf16*)(ws + alloc((size_t)384 * DIM * 2));
    size_t open  = off;
    bf16*  AGG   = (bf16*)(ws + alloc((size_t)N_NODES * nc * DIM * 2));
    int*   rp2   = (int*)(ws + alloc((size_t)(NKEY + 1) * 4));
    int*   cur2  = (int*)(ws + alloc((size_t)NKEY * 4));
    int*   deg2  = (int*)(ws + alloc((size_t)NKEY * 4));
    int*   eidx  = (int*)(ws + alloc((size_t)N_EDGES * 4));
    float* gate  = (float*)(ws + alloc((size_t)N_NODES * 4));
    float* gmax  = (float*)(ws + alloc(256));
    float* gden  = (float*)(ws + alloc(256));
    float* grep  = (float*)(ws + alloc((size_t)NGR * DIM * 4));
    bf16*  Xbf   = (bf16*)(ws + open);      // [N][800]; dead after input GEMM
    float* G1    = ACC;                     // reuse after layers

    // --- weight prep
    tcast_k<<<dim3(25, 24), 256, 0, stream>>>(W_in, WinT, 784, DIM, KIN, KIN);
    wprep_k<<<dim3(24, 24, 27), 256, 0, stream>>>(W_rel, W_loop, Wst);
    tcast_k<<<dim3(24, 12), 256, 0, stream>>>(Wg1, Wg1T, DIM, 384, DIM, DIM);

    // --- input projection (X overlaps AGG/CSR region; consumed before they're written)
    concat_k<<<N_NODES, 256, 0, stream>>>(type_vec, code_vec, Xbf);
    gemm256<0><<<768, 512, 0, stream>>>(Xbf, KIN, KIN, Xbf, KIN, WinT, KIN, ACC, DIM, KIN, 3);
    ln_gelu_k<<<N_NODES / 4, 256, 0, stream>>>(ACC, b_in, ln_in_g, ln_in_b, h_bf);

    // --- (dst,type) CSR build (after X is dead)
    hipMemsetAsync(deg2, 0, (size_t)NKEY * 4, stream);
    hist2_k<<<N_EDGES / 256, 256, 0, stream>>>(dst, etype, deg2);
    scan2_k<<<1, 1024, 0, stream>>>(deg2, rp2, cur2);
    place2_k<<<N_EDGES / 256, 256, 0, stream>>>(src, dst, etype, cur2, eidx);

    // --- RGCN layers: per chunk of nc relations, gather then accumulate-GEMM
    const int nchunks = 8 / nc;
    for (int l = 0; l < 3; ++l) {
        bf16* Wl = Wst + (size_t)l * DIM * KSTACK;
        for (int c = 0; c < nchunks; ++c) {
            const int rbase = c * nc;
            if (nc == 1)      gather2_k<1><<<N_NODES / 4, 256, 0, stream>>>(h_bf, rp2, eidx, AGG, rbase);
            else if (nc == 2) gather2_k<2><<<N_NODES / 4, 256, 0, stream>>>(h_bf, rp2, eidx, AGG, rbase);
            else              gather2_k<4><<<N_NODES / 4, 256, 0, stream>>>(h_bf, rp2, eidx, AGG, rbase);
            if (c == 0) {
                gemm256<0><<<768, 512, 0, stream>>>(
                    h_bf, DIM, DIM, AGG, nc * DIM, Wl, KSTACK, ACC, DIM, DIM + nc * DIM, 3);
            } else {
                gemm256<1><<<768, 512, 0, stream>>>(
                    AGG, nc * DIM, nc * DIM, AGG, nc * DIM,
                    Wl + (size_t)DIM * (1 + rbase), KSTACK, ACC, DIM, nc * DIM, 3);
            }
        }
        ln_gelu_k<<<N_NODES / 4, 256, 0, stream>>>(ACC, rgcn_bias + l * DIM, ln_g + l * DIM,
                                                   ln_b + l * DIM, h_bf);
    }

    // --- global attention pooling
    gemm_bt<0><<<dim3(3, 256), 256, 0, stream>>>(
        h_bf, DIM, DIM, h_bf, DIM, Wg1T, DIM, G1, 384, DIM);
    gate_k<<<N_NODES / 4, 256, 0, stream>>>(G1, bg1, Wg2, bg2, gate);
    seg_stats_k<<<NGR, 256, 0, stream>>>(gate, node_graph, gmax, gden);
    pool_k<<<NGR, 768, 0, stream>>>(h_bf, gate, node_graph, gmax, gden, grep);

    // --- classifier head
    cls_k<<<NGR, 512, 0, stream>>>(grep, Wc1, bc1, ln_c_g, ln_c_b, Wc2, bc2, (float*)d_out);
}

// Round 7
// 2686.460 us; speedup vs baseline: 3.8482x; 1.0119x over previous
//
#include <hip/hip_runtime.h>
#include <hip/hip_bf16.h>

typedef __hip_bfloat16 bf16;
typedef __attribute__((ext_vector_type(8))) __bf16 bf16x8;
typedef __attribute__((ext_vector_type(4))) float f32x4;

#define N_NODES 32768
#define N_EDGES 262144
#define DIM 768
#define NGR 64
#define KIN 800     // 784 padded to 32
#define KSTACK 6912 // self(768) + 8*768
#define NKEY (N_NODES * 8)

#define GLOBAL_AS __attribute__((address_space(1)))
#define LDS_AS __attribute__((address_space(3)))

__device__ __forceinline__ float gelu_f(float x) {
    return 0.5f * x * (1.0f + erff(x * 0.70710678118654752f));
}
__device__ __forceinline__ float bfu(unsigned short v) {
    union { unsigned u; float f; } x; x.u = (unsigned)v << 16; return x.f;
}
__device__ __forceinline__ unsigned short fbf(float f) {
    bf16 t = __float2bfloat16(f); return *(unsigned short*)&t;
}

// ---------------------------------------------------------------------------
// Transpose + cast fp32 [I][O] -> bf16 [O][ostride], zero-pad i in [I,Ipad)
__global__ __launch_bounds__(256)
void tcast_k(const float* __restrict__ in, bf16* __restrict__ out, int I, int O,
             int Ipad, int ostride) {
    __shared__ float t[32][33];
    const int i0 = blockIdx.x * 32, o0 = blockIdx.y * 32;
    const int tx = threadIdx.x & 31, ty = threadIdx.x >> 5;
#pragma unroll
    for (int q = 0; q < 4; ++q) {
        int i = i0 + ty + q * 8, o = o0 + tx;
        t[ty + q * 8][tx] = (i < I) ? in[(size_t)i * O + o] : 0.0f;
    }
    __syncthreads();
#pragma unroll
    for (int q = 0; q < 4; ++q) {
        int o = o0 + ty + q * 8, i = i0 + tx;
        if (i < Ipad) out[(size_t)o * ostride + i] = __float2bfloat16(t[tx][ty + q * 8]);
    }
}

// ---------------------------------------------------------------------------
// RGCN weights -> Wst[l][768 out][6912 K], K order: [self | r0..r7]. grid(24,24,27)
__global__ __launch_bounds__(256)
void wprep_k(const float* __restrict__ W_rel, const float* __restrict__ W_loop,
             bf16* __restrict__ Wst) {
    __shared__ float t[32][33];
    const int z = blockIdx.z, l = z / 9, q = z % 9;
    const float* in = (q < 8) ? W_rel + ((size_t)(l * 8 + q)) * DIM * DIM
                              : W_loop + (size_t)l * DIM * DIM;
    bf16* out = Wst + (size_t)l * DIM * KSTACK + (q < 8 ? (q + 1) * DIM : 0);
    const int i0 = blockIdx.x * 32, o0 = blockIdx.y * 32;
    const int tx = threadIdx.x & 31, ty = threadIdx.x >> 5;
#pragma unroll
    for (int qq = 0; qq < 4; ++qq)
        t[ty + qq * 8][tx] = in[(size_t)(i0 + ty + qq * 8) * DIM + o0 + tx];
    __syncthreads();
#pragma unroll
    for (int qq = 0; qq < 4; ++qq)
        out[(size_t)(o0 + ty + qq * 8) * KSTACK + i0 + tx] =
            __float2bfloat16(t[tx][ty + qq * 8]);
}

// ---------------------------------------------------------------------------
__global__ __launch_bounds__(256)
void concat_k(const float* __restrict__ tv, const float* __restrict__ cv, bf16* __restrict__ X) {
    const int n = blockIdx.x;
    for (int c = threadIdx.x; c < KIN; c += 256) {
        float v = 0.0f;
        if (c < 16) v = tv[(size_t)n * 16 + c];
        else if (c < 784) v = cv[(size_t)n * DIM + (c - 16)];
        X[(size_t)n * KIN + c] = __float2bfloat16(v);
    }
}

// ---------------------------------------------------------------------------
// CSR build over key = dst*8 + type
__global__ __launch_bounds__(256)
void hist2_k(const int* __restrict__ dst, const int* __restrict__ et, int* __restrict__ deg) {
    int e = blockIdx.x * 256 + threadIdx.x;
    if (e < N_EDGES) atomicAdd(&deg[dst[e] * 8 + et[e]], 1);
}

__global__ __launch_bounds__(1024)
void scan2_k(const int* __restrict__ deg, int* __restrict__ rp, int* __restrict__ cur) {
    __shared__ int part[1024];
    const int t = threadIdx.x;
    const int base_i = t * 256;
    int s = 0;
    for (int i = 0; i < 256; ++i) s += deg[base_i + i];
    part[t] = s; __syncthreads();
    for (int st = 1; st < 1024; st <<= 1) {
        int v = (t >= st) ? part[t - st] : 0;
        __syncthreads();
        part[t] += v;
        __syncthreads();
    }
    int run = part[t] - s;
    for (int i = 0; i < 256; ++i) {
        int d = deg[base_i + i];
        rp[base_i + i] = run; cur[base_i + i] = run;
        run += d;
    }
    if (t == 1023) rp[NKEY] = run;
}

__global__ __launch_bounds__(256)
void place2_k(const int* __restrict__ src, const int* __restrict__ dst,
              const int* __restrict__ et, int* __restrict__ cur, int* __restrict__ eidx) {
    int e = blockIdx.x * 256 + threadIdx.x;
    if (e >= N_EDGES) return;
    int pos = atomicAdd(&cur[dst[e] * 8 + et[e]], 1);
    eidx[pos] = src[e];
}

// ---------------------------------------------------------------------------
// Gather-aggregate for NC relations [rbase, rbase+NC), exact CSR ranges.
template <int NC>
__global__ __launch_bounds__(256)
void gather2_k(const bf16* __restrict__ h, const int* __restrict__ rp2,
               const int* __restrict__ eidx, bf16* __restrict__ AGG, int rbase) {
    const int wave = threadIdx.x >> 6, lane = threadIdx.x & 63;
    const int n = blockIdx.x * 4 + wave;
    const int c0 = 2 * lane;
    unsigned short* outrow = (unsigned short*)&AGG[(size_t)n * (NC * DIM)];
    const int* bp = &rp2[n * 8 + rbase];
#pragma unroll 1
    for (int sel = 0; sel < NC; ++sel) {
        const int s = bp[sel], e = bp[sel + 1];
        float2 f[6] = {};
        for (int t = s; t < e; ++t) {
            const unsigned short* hs = (const unsigned short*)&h[(size_t)eidx[t] * DIM];
#pragma unroll
            for (int j = 0; j < 6; ++j) {
                ushort2 u = *(const ushort2*)&hs[c0 + j * 128];
                f[j].x += bfu(u.x); f[j].y += bfu(u.y);
            }
        }
#pragma unroll
        for (int j = 0; j < 6; ++j) {
            ushort2 o; o.x = fbf(f[j].x); o.y = fbf(f[j].y);
            *(ushort2*)&outrow[sel * DIM + c0 + j * 128] = o;
        }
    }
}

// ---------------------------------------------------------------------------
// gemm256: C[M,Nn](f32) (+)= A[M,Ktot] @ BT[Nn,Ktot]^T. BM=128, BN=256, BK=32.
// 512 thr = 8 waves (2 row x 4 col). 3-deep LDS pipeline with counted vmcnt:
// stage(t+2) issued at iter t, vmcnt(6) waits only for stage(t); tail drains
// 6->3->0. Bank-conflict-free involution: write ks = k8 ^ ((row>>2)&3), read
// slot = lg ^ (l15>>2) -> 8 distinct bank-starts x 2 lanes = 2-way (free).
// XCD-chunked block swizzle. launch_bounds(512,4): 128-VGPR cap (acc in AGPR).
template <int ACCUM>
__global__ __launch_bounds__(512, 4)
void gemm256(const bf16* __restrict__ A1, int S1, int K1,
             const bf16* __restrict__ A2, int S2,
             const bf16* __restrict__ BT, int ldb,
             float* __restrict__ OUT, int Nn, int Ktot, int nbx) {
    __shared__ __align__(16) unsigned short lA[3][128 * 32];
    __shared__ __align__(16) unsigned short lB[3][256 * 32];
    const int nblk = gridDim.x;
    const int qx = nblk >> 3;
    const int bid = blockIdx.x;
    const int wgid = (bid & 7) * qx + (bid >> 3);
    const int bx = wgid % nbx, by = wgid / nbx;
    const int bn = bx * 256, bm = by * 128;
    const int tid = threadIdx.x;
    const int wave = tid >> 6, lane = tid & 63;
    const int wr = wave >> 2, wc = wave & 3;
    const int l15 = lane & 15, lg = lane >> 4;
    // conflict-free read slot (involution of the source swizzle)
    const int swz = (lg ^ (l15 >> 2)) * 8;

    f32x4 acc[4][4] = {};

    const int nt = Ktot >> 5;

    // stage K-tile t into LDS buffer buf (3 global_load_lds per thread)
    auto stage = [&](int t, int buf) {
        const int k0 = t * 32;
        const bf16* Ab; int koff, stA;
        if (k0 < K1) { Ab = A1; koff = k0; stA = S1; }
        else         { Ab = A2; koff = k0 - K1; stA = S2; }
        {
            const int row = tid >> 2, k8 = tid & 3;
            const int ks = k8 ^ ((row >> 2) & 3);  // pre-swizzled source chunk
            const bf16* ga = Ab + (size_t)(bm + row) * stA + koff + ks * 8;
            __builtin_amdgcn_global_load_lds((const GLOBAL_AS void*)ga,
                (LDS_AS void*)&lA[buf][(wave * 64) * 8], 16, 0, 0);
        }
#pragma unroll
        for (int qq = 0; qq < 2; ++qq) {
            const int c = qq * 512 + tid;
            const int row = c >> 2, k8 = c & 3;
            const int ks = k8 ^ ((row >> 2) & 3);
            const bf16* gb = BT + (size_t)(bn + row) * ldb + k0 + ks * 8;
            __builtin_amdgcn_global_load_lds((const GLOBAL_AS void*)gb,
                (LDS_AS void*)&lB[buf][((qq * 8 + wave) * 64) * 8], 16, 0, 0);
        }
    };

    stage(0, 0);
    if (nt > 1) stage(1, 1);

    int rb = 0;  // read buffer for iteration t (= t mod 3)
    for (int t = 0; t < nt; ++t) {
        if (t + 2 < nt) {
            int sb = rb + 2; if (sb >= 3) sb -= 3;
            stage(t + 2, sb);
            asm volatile("s_waitcnt vmcnt(6)" ::: "memory");
        } else if (t + 1 < nt) {
            asm volatile("s_waitcnt vmcnt(3)" ::: "memory");
        } else {
            asm volatile("s_waitcnt vmcnt(0)" ::: "memory");
        }
        __builtin_amdgcn_s_barrier();
        __builtin_amdgcn_sched_barrier(0);

        bf16x8 af[4], bfr[4];
#pragma unroll
        for (int mi = 0; mi < 4; ++mi) {
            const int r = wr * 64 + mi * 16 + l15;
            af[mi] = *reinterpret_cast<const bf16x8*>(&lA[rb][r * 32 + swz]);
        }
#pragma unroll
        for (int ni = 0; ni < 4; ++ni) {
            const int r = wc * 64 + ni * 16 + l15;
            bfr[ni] = *reinterpret_cast<const bf16x8*>(&lB[rb][r * 32 + swz]);
        }
        __builtin_amdgcn_s_setprio(1);
#pragma unroll
        for (int mi = 0; mi < 4; ++mi)
#pragma unroll
            for (int ni = 0; ni < 4; ++ni)
                acc[mi][ni] = __builtin_amdgcn_mfma_f32_16x16x32_bf16(af[mi], bfr[ni], acc[mi][ni], 0, 0, 0);
        __builtin_amdgcn_s_setprio(0);
        __builtin_amdgcn_sched_barrier(0);
        __builtin_amdgcn_s_barrier();

        rb = (rb == 2) ? 0 : rb + 1;
    }

#pragma unroll
    for (int mi = 0; mi < 4; ++mi)
#pragma unroll
        for (int ni = 0; ni < 4; ++ni) {
            const int r0 = bm + wr * 64 + mi * 16 + lg * 4;
            const int c0 = bn + wc * 64 + ni * 16 + l15;
#pragma unroll
            for (int i = 0; i < 4; ++i) {
                size_t idx = (size_t)(r0 + i) * Nn + c0;
                float v = acc[mi][ni][i];
                if (ACCUM) v += OUT[idx];
                OUT[idx] = v;
            }
        }
}

// ---------------------------------------------------------------------------
// Legacy 128x128 GEMM (gate GEMM only, Nn=384)
template <int ACCUM>
__global__ __launch_bounds__(256, 2)
void gemm_bt(const bf16* __restrict__ A1, int S1, int K1,
             const bf16* __restrict__ A2, int S2,
             const bf16* __restrict__ BT, int ldb,
             float* __restrict__ OUT, int Nn, int Ktot) {
    __shared__ __align__(16) unsigned short lA[128 * 32];
    __shared__ __align__(16) unsigned short lB[128 * 32];
    const int bn = blockIdx.x * 128;
    const int bm = blockIdx.y * 128;
    const int tid = threadIdx.x;
    const int wave = tid >> 6, lane = tid & 63;
    const int wr = wave >> 1, wc = wave & 1;
    const int l15 = lane & 15, lg = lane >> 4;

    f32x4 acc[4][4] = {};

    for (int k0 = 0; k0 < Ktot; k0 += 32) {
        const bf16* Ab; int koff, stA;
        if (k0 < K1) { Ab = A1; koff = k0; stA = S1; }
        else         { Ab = A2; koff = k0 - K1; stA = S2; }
#pragma unroll
        for (int q = 0; q < 2; ++q) {
            int c = wave * 128 + q * 64 + lane;
            int row = c >> 2, k8 = c & 3;
            const bf16* ga = Ab + (size_t)(bm + row) * stA + koff + k8 * 8;
            const bf16* gb = BT + (size_t)(bn + row) * ldb + k0 + k8 * 8;
            __builtin_amdgcn_global_load_lds((const GLOBAL_AS void*)ga,
                (LDS_AS void*)&lA[(wave * 128 + q * 64) * 8], 16, 0, 0);
            __builtin_amdgcn_global_load_lds((const GLOBAL_AS void*)gb,
                (LDS_AS void*)&lB[(wave * 128 + q * 64) * 8], 16, 0, 0);
        }
        __syncthreads();
        bf16x8 af[4], bfr[4];
#pragma unroll
        for (int mi = 0; mi < 4; ++mi)
            af[mi] = *reinterpret_cast<const bf16x8*>(&lA[(wr * 64 + mi * 16 + l15) * 32 + lg * 8]);
#pragma unroll
        for (int ni = 0; ni < 4; ++ni)
            bfr[ni] = *reinterpret_cast<const bf16x8*>(&lB[(wc * 64 + ni * 16 + l15) * 32 + lg * 8]);
#pragma unroll
        for (int mi = 0; mi < 4; ++mi)
#pragma unroll
            for (int ni = 0; ni < 4; ++ni)
                acc[mi][ni] = __builtin_amdgcn_mfma_f32_16x16x32_bf16(af[mi], bfr[ni], acc[mi][ni], 0, 0, 0);
        __syncthreads();
    }

#pragma unroll
    for (int mi = 0; mi < 4; ++mi)
#pragma unroll
        for (int ni = 0; ni < 4; ++ni) {
            const int r0 = bm + wr * 64 + mi * 16 + lg * 4;
            const int c0 = bn + wc * 64 + ni * 16 + l15;
#pragma unroll
            for (int i = 0; i < 4; ++i) {
                size_t idx = (size_t)(r0 + i) * Nn + c0;
                float v = acc[mi][ni][i];
                if (ACCUM) v += OUT[idx];
                OUT[idx] = v;
            }
        }
}

// ---------------------------------------------------------------------------
// Fused bias + LayerNorm + GELU; wave per row. grid N/4, block 256.
__global__ __launch_bounds__(256)
void ln_gelu_k(const float* __restrict__ ACC, const float* __restrict__ bias,
               const float* __restrict__ g, const float* __restrict__ b,
               bf16* __restrict__ hout) {
    const int wave = threadIdx.x >> 6, lane = threadIdx.x & 63;
    const int n = blockIdx.x * 4 + wave;
    float x[12];
    float s = 0.f, ss = 0.f;
#pragma unroll
    for (int j = 0; j < 12; ++j) {
        int c = lane + j * 64;
        x[j] = ACC[(size_t)n * DIM + c] + bias[c];
        s += x[j]; ss += x[j] * x[j];
    }
#pragma unroll
    for (int m = 1; m < 64; m <<= 1) { s += __shfl_xor(s, m, 64); ss += __shfl_xor(ss, m, 64); }
    const float mean = s * (1.f / DIM);
    const float var = ss * (1.f / DIM) - mean * mean;
    const float rstd = rsqrtf(var + 1e-5f);
#pragma unroll
    for (int j = 0; j < 12; ++j) {
        int c = lane + j * 64;
        float y = (x[j] - mean) * rstd * g[c] + b[c];
        hout[(size_t)n * DIM + c] = __float2bfloat16(gelu_f(y));
    }
}

// ---------------------------------------------------------------------------
__global__ __launch_bounds__(256)
void gate_k(const float* __restrict__ G1, const float* __restrict__ bg1,
            const float* __restrict__ Wg2, const float* __restrict__ bg2,
            float* __restrict__ gate) {
    const int wave = threadIdx.x >> 6, lane = threadIdx.x & 63;
    const int n = blockIdx.x * 4 + wave;
    float acc = 0.f;
#pragma unroll
    for (int j = 0; j < 6; ++j) {
        int c = lane + j * 64;
        float xv = G1[(size_t)n * 384 + c] + bg1[c];
        acc += gelu_f(xv) * Wg2[c];
    }
#pragma unroll
    for (int m = 1; m < 64; m <<= 1) acc += __shfl_xor(acc, m, 64);
    if (lane == 0) gate[n] = acc + bg2[0];
}

// ---------------------------------------------------------------------------
__device__ __forceinline__ int lower_bound_ng(const int* ng, int key) {
    int lo = 0, hi = N_NODES;
    while (lo < hi) { int mid = (lo + hi) >> 1; if (ng[mid] < key) lo = mid + 1; else hi = mid; }
    return lo;
}

__global__ __launch_bounds__(256)
void seg_stats_k(const float* __restrict__ gate, const int* __restrict__ ng,
                 float* __restrict__ gmax, float* __restrict__ gden) {
    __shared__ float red[256];
    const int b = blockIdx.x, t = threadIdx.x;
    const int start = lower_bound_ng(ng, b), end = lower_bound_ng(ng, b + 1);
    float m = -1e30f;
    for (int n = start + t; n < end; n += 256) m = fmaxf(m, gate[n]);
    red[t] = m; __syncthreads();
    for (int s = 128; s > 0; s >>= 1) { if (t < s) red[t] = fmaxf(red[t], red[t + s]); __syncthreads(); }
    const float gm = red[0]; __syncthreads();
    float ssum = 0.f;
    for (int n = start + t; n < end; n += 256) ssum += expf(gate[n] - gm);
    red[t] = ssum; __syncthreads();
    for (int s = 128; s > 0; s >>= 1) { if (t < s) red[t] += red[t + s]; __syncthreads(); }
    if (t == 0) { gmax[b] = gm; gden[b] = fmaxf(red[0], 1e-30f); }
}

__global__ __launch_bounds__(768)
void pool_k(const bf16* __restrict__ h, const float* __restrict__ gate,
            const int* __restrict__ ng, const float* __restrict__ gmax,
            const float* __restrict__ gden, float* __restrict__ grep) {
    const int b = blockIdx.x, c = threadIdx.x;
    const int start = lower_bound_ng(ng, b), end = lower_bound_ng(ng, b + 1);
    const float gm = gmax[b], inv = 1.0f / gden[b];
    const unsigned short* hv = (const unsigned short*)h;
    float a0 = 0.f, a1 = 0.f;
    int n = start;
    for (; n + 1 < end; n += 2) {
        float w0 = expf(gate[n] - gm) * inv;
        float w1 = expf(gate[n + 1] - gm) * inv;
        a0 += w0 * bfu(hv[(size_t)n * DIM + c]);
        a1 += w1 * bfu(hv[(size_t)(n + 1) * DIM + c]);
    }
    if (n < end) a0 += expf(gate[n] - gm) * inv * bfu(hv[(size_t)n * DIM + c]);
    grep[(size_t)b * DIM + c] = a0 + a1;
}

// ---------------------------------------------------------------------------
__global__ __launch_bounds__(512)
void cls_k(const float* __restrict__ grep, const float* __restrict__ Wc1,
           const float* __restrict__ bc1, const float* __restrict__ lng,
           const float* __restrict__ lnb, const float* __restrict__ Wc2,
           const float* __restrict__ bc2, float* __restrict__ out) {
    __shared__ float gr[DIM];
    __shared__ float red[512];
    const int b = blockIdx.x, j = threadIdx.x;
    for (int c = j; c < DIM; c += 512) gr[c] = grep[(size_t)b * DIM + c];
    __syncthreads();
    float a = bc1[j];
#pragma unroll 4
    for (int k = 0; k < DIM; ++k) a = fmaf(gr[k], Wc1[(size_t)k * 512 + j], a);
    red[j] = a; __syncthreads();
    for (int s = 256; s > 0; s >>= 1) { if (j < s) red[j] += red[j + s]; __syncthreads(); }
    const float mean = red[0] * (1.f / 512.f);
    __syncthreads();
    red[j] = (a - mean) * (a - mean); __syncthreads();
    for (int s = 256; s > 0; s >>= 1) { if (j < s) red[j] += red[j + s]; __syncthreads(); }
    const float rstd = rsqrtf(red[0] * (1.f / 512.f) + 1e-5f);
    __syncthreads();
    const float z = gelu_f((a - mean) * rstd * lng[j] + lnb[j]);
    red[j] = z * Wc2[2 * j + 0]; __syncthreads();
    for (int s = 256; s > 0; s >>= 1) { if (j < s) red[j] += red[j + s]; __syncthreads(); }
    const float l0 = red[0] + bc2[0];
    __syncthreads();
    red[j] = z * Wc2[2 * j + 1]; __syncthreads();
    for (int s = 256; s > 0; s >>= 1) { if (j < s) red[j] += red[j + s]; __syncthreads(); }
    if (j == 0) {
        const float l1 = red[0] + bc2[1];
        const float mx = fmaxf(l0, l1);
        const float lse = mx + logf(expf(l0 - mx) + expf(l1 - mx));
        out[2 * b + 0] = l0 - lse;
        out[2 * b + 1] = l1 - lse;
    }
}

// ---------------------------------------------------------------------------
extern "C" void kernel_launch(void* const* d_in, const int* in_sizes, int n_in,
                              void* d_out, int out_size, void* d_ws, size_t ws_size,
                              hipStream_t stream) {
    const float* type_vec = (const float*)d_in[0];
    const float* code_vec = (const float*)d_in[1];
    const float* W_in     = (const float*)d_in[2];
    const float* b_in     = (const float*)d_in[3];
    const float* ln_in_g  = (const float*)d_in[4];
    const float* ln_in_b  = (const float*)d_in[5];
    const float* W_rel    = (const float*)d_in[6];
    const float* W_loop   = (const float*)d_in[7];
    const float* rgcn_bias= (const float*)d_in[8];
    const float* ln_g     = (const float*)d_in[9];
    const float* ln_b     = (const float*)d_in[10];
    const float* Wg1      = (const float*)d_in[11];
    const float* bg1      = (const float*)d_in[12];
    const float* Wg2      = (const float*)d_in[13];
    const float* bg2      = (const float*)d_in[14];
    const float* Wc1      = (const float*)d_in[15];
    const float* bc1      = (const float*)d_in[16];
    const float* ln_c_g   = (const float*)d_in[17];
    const float* ln_c_b   = (const float*)d_in[18];
    const float* Wc2      = (const float*)d_in[19];
    const float* bc2      = (const float*)d_in[20];
    const int* src        = (const int*)d_in[21];
    const int* dst        = (const int*)d_in[22];
    const int* etype      = (const int*)d_in[23];
    const int* node_graph = (const int*)d_in[24];

    char* ws = (char*)d_ws;

    // pick relation-chunk width nc by workspace size
    auto need = [](int nc) -> size_t {
        size_t base = 0;
        auto al = [&](size_t sz) { base = (base + sz + 255) & ~(size_t)255; };
        al((size_t)N_NODES * DIM * 2);        // H
        al((size_t)N_NODES * DIM * 4);        // ACC
        al((size_t)DIM * KIN * 2);            // WIN
        al((size_t)3 * DIM * KSTACK * 2);     // WST
        al((size_t)384 * DIM * 2);            // WG1
        size_t open = base;
        al((size_t)N_NODES * nc * DIM * 2);   // AGG
        al((size_t)(NKEY + 1) * 4);           // RP2
        al((size_t)NKEY * 4);                 // CUR2
        al((size_t)NKEY * 4);                 // DEG2
        al((size_t)N_EDGES * 4);              // EIX
        al((size_t)N_NODES * 4);              // GATE
        al(256); al(256);                     // GMAX, GDEN
        al((size_t)NGR * DIM * 4);            // GREP
        size_t xend = open + (size_t)N_NODES * KIN * 2;
        return base > xend ? base : xend;
    };
    int nc = 1;
    if (ws_size >= need(4)) nc = 4;
    else if (ws_size >= need(2)) nc = 2;

    // layout
    size_t off = 0;
    auto alloc = [&](size_t sz) { size_t r = off; off = (off + sz + 255) & ~(size_t)255; return r; };
    bf16*  h_bf  = (bf16*)(ws + alloc((size_t)N_NODES * DIM * 2));
    float* ACC   = (float*)(ws + alloc((size_t)N_NODES * DIM * 4));
    bf16*  WinT  = (bf16*)(ws + alloc((size_t)DIM * KIN * 2));
    bf16*  Wst   = (bf16*)(ws + alloc((size_t)3 * DIM * KSTACK * 2));
    bf16*  Wg1T  = (bf16*)(ws + alloc((size_t)384 * DIM * 2));
    size_t open  = off;
    bf16*  AGG   = (bf16*)(ws + alloc((size_t)N_NODES * nc * DIM * 2));
    int*   rp2   = (int*)(ws + alloc((size_t)(NKEY + 1) * 4));
    int*   cur2  = (int*)(ws + alloc((size_t)NKEY * 4));
    int*   deg2  = (int*)(ws + alloc((size_t)NKEY * 4));
    int*   eidx  = (int*)(ws + alloc((size_t)N_EDGES * 4));
    float* gate  = (float*)(ws + alloc((size_t)N_NODES * 4));
    float* gmax  = (float*)(ws + alloc(256));
    float* gden  = (float*)(ws + alloc(256));
    float* grep  = (float*)(ws + alloc((size_t)NGR * DIM * 4));
    bf16*  Xbf   = (bf16*)(ws + open);      // [N][800]; dead after input GEMM
    float* G1    = ACC;                     // reuse after layers

    // --- weight prep
    tcast_k<<<dim3(25, 24), 256, 0, stream>>>(W_in, WinT, 784, DIM, KIN, KIN);
    wprep_k<<<dim3(24, 24, 27), 256, 0, stream>>>(W_rel, W_loop, Wst);
    tcast_k<<<dim3(24, 12), 256, 0, stream>>>(Wg1, Wg1T, DIM, 384, DIM, DIM);

    // --- input projection (X overlaps AGG/CSR region; consumed before they're written)
    concat_k<<<N_NODES, 256, 0, stream>>>(type_vec, code_vec, Xbf);
    gemm256<0><<<768, 512, 0, stream>>>(Xbf, KIN, KIN, Xbf, KIN, WinT, KIN, ACC, DIM, KIN, 3);
    ln_gelu_k<<<N_NODES / 4, 256, 0, stream>>>(ACC, b_in, ln_in_g, ln_in_b, h_bf);

    // --- (dst,type) CSR build (after X is dead)
    hipMemsetAsync(deg2, 0, (size_t)NKEY * 4, stream);
    hist2_k<<<N_EDGES / 256, 256, 0, stream>>>(dst, etype, deg2);
    scan2_k<<<1, 1024, 0, stream>>>(deg2, rp2, cur2);
    place2_k<<<N_EDGES / 256, 256, 0, stream>>>(src, dst, etype, cur2, eidx);

    // --- RGCN layers: per chunk of nc relations, gather then accumulate-GEMM
    const int nchunks = 8 / nc;
    for (int l = 0; l < 3; ++l) {
        bf16* Wl = Wst + (size_t)l * DIM * KSTACK;
        for (int c = 0; c < nchunks; ++c) {
            const int rbase = c * nc;
            if (nc == 1)      gather2_k<1><<<N_NODES / 4, 256, 0, stream>>>(h_bf, rp2, eidx, AGG, rbase);
            else if (nc == 2) gather2_k<2><<<N_NODES / 4, 256, 0, stream>>>(h_bf, rp2, eidx, AGG, rbase);
            else              gather2_k<4><<<N_NODES / 4, 256, 0, stream>>>(h_bf, rp2, eidx, AGG, rbase);
            if (c == 0) {
                gemm256<0><<<768, 512, 0, stream>>>(
                    h_bf, DIM, DIM, AGG, nc * DIM, Wl, KSTACK, ACC, DIM, DIM + nc * DIM, 3);
            } else {
                gemm256<1><<<768, 512, 0, stream>>>(
                    AGG, nc * DIM, nc * DIM, AGG, nc * DIM,
                    Wl + (size_t)DIM * (1 + rbase), KSTACK, ACC, DIM, nc * DIM, 3);
            }
        }
        ln_gelu_k<<<N_NODES / 4, 256, 0, stream>>>(ACC, rgcn_bias + l * DIM, ln_g + l * DIM,
                                                   ln_b + l * DIM, h_bf);
    }

    // --- global attention pooling
    gemm_bt<0><<<dim3(3, 256), 256, 0, stream>>>(
        h_bf, DIM, DIM, h_bf, DIM, Wg1T, DIM, G1, 384, DIM);
    gate_k<<<N_NODES / 4, 256, 0, stream>>>(G1, bg1, Wg2, bg2, gate);
    seg_stats_k<<<NGR, 256, 0, stream>>>(gate, node_graph, gmax, gden);
    pool_k<<<NGR, 768, 0, stream>>>(h_bf, gate, node_graph, gmax, gden, grep);

    // --- classifier head
    cls_k<<<NGR, 512, 0, stream>>>(grep, Wc1, bc1, ln_c_g, ln_c_b, Wc2, bc2, (float*)d_out);
}